// Round 9
// baseline (46.737 us; speedup 1.0000x reference)
//
#include <hip/hip_runtime.h>
#include <hip/hip_bf16.h>
#include <hip/hip_fp16.h>

typedef _Float16 f16x8 __attribute__((ext_vector_type(8)));
typedef float f32x4 __attribute__((ext_vector_type(4)));

#define N_PTS 32768
#define NCHUNK 65       // 64 h-chunks + 1 bias chunk (h == 1)
#define ROWS 64         // rows per block
#define H_STRIDE 72     // f16; 144 B rows: 16B-aligned b128 writes

// ---- prep: repack W2 (fp32 [4096][64]) + b2 (fp32 [4096]) into f16 MFMA
// fragment layout (unchanged from R6/R7, proven correct).
//   chunk c, frag q = s*4 + nt at bytes [c*8192 + q*1024 ...): lane holds
//   Wf[c*64 + s*32 + kgrp*8 + j][nt*16 + (lane&15)], j=0..7 (16 B).
__global__ __launch_bounds__(256) void prep_kernel(
    const float* __restrict__ W2, const float* __restrict__ b2,
    _Float16* __restrict__ wsB) {
  __shared__ _Float16 w_lds[64][H_STRIDE];
  const int c   = blockIdx.x;
  const int tid = threadIdx.x;
  {
    const float* src = (c < 64) ? (W2 + c * 4096 + tid * 16) : (b2 + tid * 16);
    int kl = tid >> 2, o = (tid & 3) * 16;
    f16x8 v0, v1;
    #pragma unroll
    for (int j = 0; j < 8; ++j) {
      v0[j] = (_Float16)src[j];
      v1[j] = (_Float16)src[8 + j];
    }
    *(f16x8*)(&w_lds[kl][o])     = v0;
    *(f16x8*)(&w_lds[kl][o + 8]) = v1;
  }
  __syncthreads();
  #pragma unroll
  for (int u = 0; u < 2; ++u) {
    int t = tid + u * 256;           // dest chunk index within c: 0..511
    int q = t >> 6, lane = t & 63;
    int klbase = (q >> 2) * 32 + ((lane >> 4) & 3) * 8;
    int o      = (q & 3) * 16 + (lane & 15);
    f16x8 v;
    #pragma unroll
    for (int j = 0; j < 8; ++j) v[j] = w_lds[klbase + j][o];
    *(f16x8*)(wsB + c * 4096 + t * 8) = v;
  }
}

// ---- main fused kernel: m97-style LDS double-buffer via global_load_lds ----
// 512 blocks x 256 threads (4 waves), 2 blocks/CU. Block = 64 rows x 64 cols.
// Wave w owns cols [16w, 16w+16) for ALL 64 rows (m-rep 4, n-rep 1): acc is
// final, no reduce. Per step: stage next chunk (2x global_load_lds width=16),
// read own 2 KB B-slice (2x ds_read_b128), 8 MFMA, 1 barrier (drains loads).
__global__ __launch_bounds__(256) void main_kernel(
    const float* __restrict__ x, const float* __restrict__ gridp,
    const float* __restrict__ W1, const float* __restrict__ b1,
    const _Float16* __restrict__ wsB, float* __restrict__ out) {

  __shared__ _Float16 bbuf[2][4096];             // 2 x 8 KB chunk dbuf
  __shared__ _Float16 h_lds[ROWS][H_STRIDE];     // 9216 B ; total ~25.5 KB

  const int tid  = threadIdx.x;
  const int lane = tid & 63;
  const int wave = tid >> 6;
  const int rowblk = blockIdx.x * ROWS;
  const int mrow = lane & 15;        // A row within 16-tile / D col
  const int kgrp = lane >> 4;        // 0..3

  const char* wsb = (const char*)wsB;

  // stage chunk c into bbuf[par]: wave w covers bytes [w*1024, +1024) and
  // [4096 + w*1024, +1024). LDS dest is wave-uniform base (+ lane*16 by HW);
  // global src is per-lane.
  auto STAGE = [&](int c, int par) {
    const char* src = wsb + c * 8192 + wave * 1024 + lane * 16;
    char* dst = (char*)&bbuf[par][0] + wave * 1024;
    __builtin_amdgcn_global_load_lds(
        (const __attribute__((address_space(1))) void*)src,
        (__attribute__((address_space(3))) void*)dst, 16, 0, 0);
    __builtin_amdgcn_global_load_lds(
        (const __attribute__((address_space(1))) void*)(src + 4096),
        (__attribute__((address_space(3))) void*)(dst + 4096), 16, 0, 0);
  };

  STAGE(0, 0);   // prologue stage; drained by the prologue barrier

  // h phase: h[row][k] = gelu(grid @ W1 + b1). 4 threads/row, 16 k each.
  {
    int row = tid >> 2;
    int kb  = (tid & 3) * 16;
    int r = rowblk + row;
    float g0 = gridp[r * 3 + 0], g1 = gridp[r * 3 + 1], g2 = gridp[r * 3 + 2];
    f16x8 h0, h1;
    #pragma unroll
    for (int q = 0; q < 16; ++q) {
      int k = kb + q;
      float v = g0 * W1[k] + g1 * W1[64 + k] + g2 * W1[128 + k] + b1[k];
      float h = 0.5f * v * (1.0f + erff(v * 0.7071067811865476f));
      if (q < 8) h0[q] = (_Float16)h; else h1[q - 8] = (_Float16)h;
    }
    *(f16x8*)(&h_lds[row][kb])     = h0;
    *(f16x8*)(&h_lds[row][kb + 8]) = h1;
  }

  // x fragments (all 64 rows of the block, this wave's K-carve):
  // xf[m][s][j] = x[rowblk + m*16 + mrow][s*32 + kgrp*8 + j]
  f16x8 xf[4][2];
  #pragma unroll
  for (int m = 0; m < 4; ++m)
    #pragma unroll
    for (int s = 0; s < 2; ++s) {
      const float* xp = x + (rowblk + m * 16 + mrow) * 64 + s * 32 + kgrp * 8;
      f32x4 a = *(const f32x4*)(xp);
      f32x4 b = *(const f32x4*)(xp + 4);
      f16x8 v;
      #pragma unroll
      for (int j = 0; j < 4; ++j) {
        v[j]     = (_Float16)a[j];
        v[4 + j] = (_Float16)b[j];
      }
      xf[m][s] = v;
    }

  __syncthreads();   // h_lds visible + chunk 0 staged (barrier drains vmcnt)

  f32x4 acc[4];
  #pragma unroll
  for (int m = 0; m < 4; ++m) acc[m] = (f32x4){0.f, 0.f, 0.f, 0.f};

  // main loop: 64 h-chunks; chunk t in bbuf[t&1], stage t+1 into bbuf[~t&1]
  for (int t = 0; t < 64; ++t) {
    STAGE(t + 1, (t + 1) & 1);       // t=63 stages the bias chunk (c=64)
    const _Float16* bb = &bbuf[t & 1][0];
    f16x8 bf0 = *(const f16x8*)(bb + (wave)     * 512 + lane * 8);  // q=wave
    f16x8 bf1 = *(const f16x8*)(bb + (4 + wave) * 512 + lane * 8);  // q=4+wave
    #pragma unroll
    for (int m = 0; m < 4; ++m) {
      _Float16 hh = h_lds[m * 16 + mrow][t];
      f16x8 hs = {hh, hh, hh, hh, hh, hh, hh, hh};
      acc[m] = __builtin_amdgcn_mfma_f32_16x16x32_f16(xf[m][0] * hs, bf0, acc[m], 0, 0, 0);
      acc[m] = __builtin_amdgcn_mfma_f32_16x16x32_f16(xf[m][1] * hs, bf1, acc[m], 0, 0, 0);
    }
    __syncthreads();                 // readers done + staged loads drained
  }

  // bias chunk (c=64, h == 1): in bbuf[0]; A-frag = xf directly
  {
    const _Float16* bb = &bbuf[0][0];
    f16x8 bf0 = *(const f16x8*)(bb + (wave)     * 512 + lane * 8);
    f16x8 bf1 = *(const f16x8*)(bb + (4 + wave) * 512 + lane * 8);
    #pragma unroll
    for (int m = 0; m < 4; ++m) {
      acc[m] = __builtin_amdgcn_mfma_f32_16x16x32_f16(xf[m][0], bf0, acc[m], 0, 0, 0);
      acc[m] = __builtin_amdgcn_mfma_f32_16x16x32_f16(xf[m][1], bf1, acc[m], 0, 0, 0);
    }
  }

  // epilogue: wave w stores cols [16w, 16w+16), rows per C/D layout
  #pragma unroll
  for (int m = 0; m < 4; ++m) {
    int row = rowblk + m * 16 + kgrp * 4;
    #pragma unroll
    for (int r = 0; r < 4; ++r)
      out[(row + r) * 64 + wave * 16 + mrow] = acc[m][r];
  }
}

extern "C" void kernel_launch(void* const* d_in, const int* in_sizes, int n_in,
                              void* d_out, int out_size, void* d_ws, size_t ws_size,
                              hipStream_t stream) {
  const float* x    = (const float*)d_in[0];
  const float* grid = (const float*)d_in[1];
  const float* W1   = (const float*)d_in[2];
  const float* b1   = (const float*)d_in[3];
  const float* W2   = (const float*)d_in[4];
  const float* b2   = (const float*)d_in[5];
  float* out = (float*)d_out;
  _Float16* wsB = (_Float16*)d_ws;   // needs 65*4096*2 = 532480 bytes

  hipLaunchKernelGGL(prep_kernel, dim3(NCHUNK), dim3(256), 0, stream,
                     W2, b2, wsB);
  hipLaunchKernelGGL(main_kernel, dim3(N_PTS / ROWS), dim3(256), 0, stream,
                     x, grid, W1, b1, wsB, out);
}

// Round 10
// 40.241 us; speedup vs baseline: 1.1614x; 1.1614x over previous
//
#include <hip/hip_runtime.h>
#include <hip/hip_bf16.h>
#include <hip/hip_fp16.h>

typedef _Float16 f16x8 __attribute__((ext_vector_type(8)));
typedef _Float16 f16x4v __attribute__((ext_vector_type(4)));
typedef float f32x4 __attribute__((ext_vector_type(4)));

#define N_PTS 32768
#define NCHUNK 65       // 64 h-chunks + 1 bias chunk (h == 1)
#define ROWS_BLK 128    // rows per block (2 M-groups x 64)
#define H_STRIDE 68     // f16; 136 B rows -> h b64 reads conflict-free

// ---- prep: repack W2 (fp32 [4096][64]) + b2 (fp32 [4096]) into f16 MFMA
// fragment layout (unchanged since R6, proven correct).
//   chunk c, frag q = s*4 + nt at bytes [c*8192 + q*1024): lane holds
//   Wf[c*64 + s*32 + kgrp*8 + j][nt*16 + (lane&15)], j=0..7 (16 B).
__global__ __launch_bounds__(256) void prep_kernel(
    const float* __restrict__ W2, const float* __restrict__ b2,
    _Float16* __restrict__ wsB) {
  __shared__ _Float16 w_lds[64][72];
  const int c   = blockIdx.x;
  const int tid = threadIdx.x;
  {
    const float* src = (c < 64) ? (W2 + c * 4096 + tid * 16) : (b2 + tid * 16);
    int kl = tid >> 2, o = (tid & 3) * 16;
    f16x8 v0, v1;
    #pragma unroll
    for (int j = 0; j < 8; ++j) {
      v0[j] = (_Float16)src[j];
      v1[j] = (_Float16)src[8 + j];
    }
    *(f16x8*)(&w_lds[kl][o])     = v0;
    *(f16x8*)(&w_lds[kl][o + 8]) = v1;
  }
  __syncthreads();
  #pragma unroll
  for (int u = 0; u < 2; ++u) {
    int t = tid + u * 256;           // dest chunk index within c: 0..511
    int q = t >> 6, lane = t & 63;
    int klbase = (q >> 2) * 32 + ((lane >> 4) & 3) * 8;
    int o      = (q & 3) * 16 + (lane & 15);
    f16x8 v;
    #pragma unroll
    for (int j = 0; j < 8; ++j) v[j] = w_lds[klbase + j][o];
    *(f16x8*)(wsB + c * 4096 + t * 8) = v;
  }
}

// ---- main fused kernel: T3+T4 K-loop (counted vmcnt, raw barrier) ----
// 256 blocks x 512 threads (8 waves = 2 mg x 4 nt), 128 rows/block, 1/CU.
// 16 steps x 4 chunks (32 KB) triple-buffered via global_load_lds (2-deep
// prefetch). Per step: stage(t+2), compute(t) [8 ds_read_b128 B + 4
// ds_read_b64 h + 32 MFMA], then s_waitcnt vmcnt(4) + s_barrier (stage(t+2)
// stays in flight across the barrier - never drain to 0 in the loop).
__global__ __launch_bounds__(512) void main_kernel(
    const float* __restrict__ x, const float* __restrict__ gridp,
    const float* __restrict__ W1, const float* __restrict__ b1,
    const _Float16* __restrict__ wsB, float* __restrict__ out) {

  __shared__ _Float16 bbuf[3][16384];             // 3 x 32 KB step buffers
  __shared__ _Float16 h_lds[ROWS_BLK][H_STRIDE];  // 17408 B ; total 115712 B

  const int tid  = threadIdx.x;
  const int lane = tid & 63;
  const int wave = tid >> 6;         // 0..7
  const int mg   = wave >> 2;        // M-group: rows [64*mg, 64*mg+64)
  const int nt   = wave & 3;         // N-tile: cols [16*nt, 16*nt+16)
  const int rowblk   = blockIdx.x * ROWS_BLK;
  const int growbase = rowblk + mg * 64;
  const int mrow = lane & 15;        // A row within 16-tile / D col
  const int kgrp = lane >> 4;        // 0..3

  const char* wsb = (const char*)wsB;

  // stage step t (chunks 4t..4t+3, 32 KB) into bbuf[t%3]; wave covers 4 KB.
  // LDS dest is wave-uniform (HW adds lane*16); global src is per-lane.
  auto STAGE = [&](int t) {
    const char* src = wsb + t * 32768 + wave * 4096 + lane * 16;
    char* dst = (char*)&bbuf[t % 3][0] + wave * 4096;
    #pragma unroll
    for (int i = 0; i < 4; ++i)
      __builtin_amdgcn_global_load_lds(
          (const __attribute__((address_space(1))) void*)(src + i * 1024),
          (__attribute__((address_space(3))) void*)(dst + i * 1024), 16, 0, 0);
  };

  STAGE(0);
  STAGE(1);

  // h phase: h[row][k] = gelu(grid @ W1 + b1). 4 threads/row, 16 k each.
  {
    int row = tid >> 2;              // 0..127
    int kb  = (tid & 3) * 16;
    int r = rowblk + row;
    float g0 = gridp[r * 3 + 0], g1 = gridp[r * 3 + 1], g2 = gridp[r * 3 + 2];
    f16x8 h0, h1;
    #pragma unroll
    for (int q = 0; q < 16; ++q) {
      int k = kb + q;
      float v = g0 * W1[k] + g1 * W1[64 + k] + g2 * W1[128 + k] + b1[k];
      float h = 0.5f * v * (1.0f + erff(v * 0.7071067811865476f));
      if (q < 8) h0[q] = (_Float16)h; else h1[q - 8] = (_Float16)h;
    }
    *(f16x8*)(&h_lds[row][kb])     = h0;   // 136 B rows: 16B-aligned stores
    *(f16x8*)(&h_lds[row][kb + 8]) = h1;
  }

  // x fragments: xf[m][s][j] = x[growbase + m*16+mrow][s*32 + kgrp*8 + j]
  f16x8 xf[4][2];
  #pragma unroll
  for (int m = 0; m < 4; ++m)
    #pragma unroll
    for (int s = 0; s < 2; ++s) {
      const float* xp = x + (growbase + m * 16 + mrow) * 64 + s * 32 + kgrp * 8;
      f32x4 a = *(const f32x4*)(xp);
      f32x4 b = *(const f32x4*)(xp + 4);
      f16x8 v;
      #pragma unroll
      for (int j = 0; j < 4; ++j) {
        v[j]     = (_Float16)a[j];
        v[4 + j] = (_Float16)b[j];
      }
      xf[m][s] = v;
    }

  // prologue barrier: h_lds visible; steps 0,1 staged (prologue loads after
  // the stages force in-order retirement, so vmcnt(0) is already near-true)
  asm volatile("s_waitcnt vmcnt(0) lgkmcnt(0)" ::: "memory");
  __builtin_amdgcn_s_barrier();
  __builtin_amdgcn_sched_barrier(0);

  f32x4 acc[4];
  #pragma unroll
  for (int m = 0; m < 4; ++m) acc[m] = (f32x4){0.f, 0.f, 0.f, 0.f};

  auto COMPUTE_STEP = [&](int t) {
    const _Float16* bb = &bbuf[t % 3][0];
    f16x4v hv[4];                    // h[row][4t..4t+4): one b64 per m
    #pragma unroll
    for (int m = 0; m < 4; ++m)
      hv[m] = *(const f16x4v*)(&h_lds[mg * 64 + m * 16 + mrow][4 * t]);
    #pragma unroll
    for (int c = 0; c < 4; ++c) {
      f16x8 bf0 = *(const f16x8*)(bb + c * 4096 + nt * 512 + lane * 8);
      f16x8 bf1 = *(const f16x8*)(bb + c * 4096 + (4 + nt) * 512 + lane * 8);
      #pragma unroll
      for (int m = 0; m < 4; ++m) {
        _Float16 hh = hv[m][c];
        f16x8 hs = {hh, hh, hh, hh, hh, hh, hh, hh};
        acc[m] = __builtin_amdgcn_mfma_f32_16x16x32_f16(xf[m][0] * hs, bf0, acc[m], 0, 0, 0);
        acc[m] = __builtin_amdgcn_mfma_f32_16x16x32_f16(xf[m][1] * hs, bf1, acc[m], 0, 0, 0);
      }
    }
  };

  // main loop: step t reads bbuf[t%3] (staged at t-2, waited at end of t-1)
  #pragma unroll
  for (int t = 0; t < 16; ++t) {
    if (t + 2 < 16) STAGE(t + 2);
    COMPUTE_STEP(t);
    if (t < 15) {
      if (t < 14) asm volatile("s_waitcnt vmcnt(4)" ::: "memory");
      else        asm volatile("s_waitcnt vmcnt(0)" ::: "memory");
      __builtin_amdgcn_s_barrier();
      __builtin_amdgcn_sched_barrier(0);
    }
  }

  // bias chunk (c = 64, h == 1): register-direct B, A-frag = xf unscaled
  {
    const _Float16* bsrc = wsB + 64 * 4096;
    f16x8 bb0 = *(const f16x8*)(bsrc + nt * 512 + lane * 8);
    f16x8 bb1 = *(const f16x8*)(bsrc + (4 + nt) * 512 + lane * 8);
    #pragma unroll
    for (int m = 0; m < 4; ++m) {
      acc[m] = __builtin_amdgcn_mfma_f32_16x16x32_f16(xf[m][0], bb0, acc[m], 0, 0, 0);
      acc[m] = __builtin_amdgcn_mfma_f32_16x16x32_f16(xf[m][1], bb1, acc[m], 0, 0, 0);
    }
  }

  // epilogue: wave stores cols [16nt, 16nt+16) of its 64 rows
  #pragma unroll
  for (int m = 0; m < 4; ++m) {
    int row = growbase + m * 16 + kgrp * 4;
    #pragma unroll
    for (int r = 0; r < 4; ++r)
      out[(row + r) * 64 + nt * 16 + mrow] = acc[m][r];
  }
}

extern "C" void kernel_launch(void* const* d_in, const int* in_sizes, int n_in,
                              void* d_out, int out_size, void* d_ws, size_t ws_size,
                              hipStream_t stream) {
  const float* x    = (const float*)d_in[0];
  const float* grid = (const float*)d_in[1];
  const float* W1   = (const float*)d_in[2];
  const float* b1   = (const float*)d_in[3];
  const float* W2   = (const float*)d_in[4];
  const float* b2   = (const float*)d_in[5];
  float* out = (float*)d_out;
  _Float16* wsB = (_Float16*)d_ws;   // needs 65*4096*2 = 532480 bytes

  hipLaunchKernelGGL(prep_kernel, dim3(NCHUNK), dim3(256), 0, stream,
                     W2, b2, wsB);
  hipLaunchKernelGGL(main_kernel, dim3(N_PTS / ROWS_BLK), dim3(512), 0, stream,
                     x, grid, W1, b1, wsB, out);
}